// Round 1
// baseline (285.353 us; speedup 1.0000x reference)
//
#include <hip/hip_runtime.h>
#include <hip/hip_bf16.h>
#include <math.h>

#define ALPHA 0.01f

// ---------------------------------------------------------------------------
// init: zero counts, emit output0 (= iftargets[:,0] as float), compute frv.
// frv[l][p] = product of normalized rvec[l..2][p] (ETYPES=(0,2,4): rv only,
// no conjugates; frv[3] = 1+0j). Layout frv[l*64 + p*2 + c].
// ---------------------------------------------------------------------------
__global__ void init_kernel(const int* __restrict__ ift,
                            const float* __restrict__ rvec,
                            float* __restrict__ out0,
                            float* __restrict__ frv,
                            int* __restrict__ counts, int N) {
    int gid = blockIdx.x * blockDim.x + threadIdx.x;
    for (int i = gid; i < N; i += gridDim.x * blockDim.x) {
        counts[i] = 0;
        out0[i] = (float)ift[2 * i];
    }
    if (blockIdx.x == 0 && threadIdx.x < 32) {
        int p = threadIdx.x;
        float fr = 1.f, fi = 0.f;
        frv[3 * 64 + 2 * p]     = 1.f;
        frv[3 * 64 + 2 * p + 1] = 0.f;
        for (int l = 2; l >= 0; --l) {
            float rr = rvec[l * 64 + 2 * p];
            float ri = rvec[l * 64 + 2 * p + 1];
            float inv = rsqrtf(rr * rr + ri * ri);
            rr *= inv; ri *= inv;
            float nr = fr * rr - fi * ri;
            float ni = fr * ri + fi * rr;
            fr = nr; fi = ni;
            frv[l * 64 + 2 * p]     = fr;
            frv[l * 64 + 2 * p + 1] = fi;
        }
    }
}

// ---------------------------------------------------------------------------
// edge: one 64-lane wave per edge. lane = feature dim d.
//   rot = x*fr + sgn*partner*fi   (partner via shfl_xor(x,1))
//   hidden = mean_l rot;  a[h] = leaky(center.w1[h] + hidden.w2[h])
// ---------------------------------------------------------------------------
__global__ void edge_kernel(const int* __restrict__ mp,
                            const float* __restrict__ feat,
                            const float* __restrict__ frv,
                            const float* __restrict__ w1,
                            const float* __restrict__ w2,
                            float* __restrict__ hidden,
                            float* __restrict__ abuf,
                            int* __restrict__ counts, int E) {
    int wid = (int)((blockIdx.x * blockDim.x + threadIdx.x) >> 6);
    int lane = threadIdx.x & 63;
    if (wid >= E) return;
    const int* mpe = mp + (size_t)wid * 4;
    float sgn = (lane & 1) ? 1.f : -1.f;
    float hsum = 0.f;
    float center = 0.f;
#pragma unroll
    for (int l = 0; l < 4; ++l) {
        int node = mpe[l];
        float x = feat[(size_t)node * 64 + lane];
        float partner = __shfl_xor(x, 1);
        float fr = frv[l * 64 + (lane & ~1)];
        float fi = frv[l * 64 + (lane | 1)];
        hsum += x * fr + sgn * partner * fi;
        if (l == 3) center = x;
    }
    float hv = hsum * 0.25f;
    hidden[(size_t)wid * 64 + lane] = hv;

    float aval = 0.f;
#pragma unroll
    for (int hh = 0; hh < 8; ++hh) {
        float p = center * w1[hh * 64 + lane] + hv * w2[hh * 64 + lane];
#pragma unroll
        for (int m = 32; m >= 1; m >>= 1) p += __shfl_xor(p, m);
        if (lane == hh) aval = p;          // keep head hh's result in lane hh
    }
    if (lane < 8) {
        aval = aval > 0.f ? aval : ALPHA * aval;
        abuf[(size_t)wid * 8 + lane] = aval;
    }
    if (lane == 0) atomicAdd(&counts[mpe[3]], 1);
}

// ---------------------------------------------------------------------------
// scan: single block, 1024 threads. Exclusive scan of counts -> offsets[N+1],
// and a second copy (cursor) for the scatter pass.
// ---------------------------------------------------------------------------
__global__ void scan_kernel(const int* __restrict__ counts,
                            int* __restrict__ offsets,
                            int* __restrict__ cursor, int N) {
    const int T = 1024;
    int tid = threadIdx.x;
    int per = (N + T - 1) / T;
    int beg = tid * per;
    int end = min(beg + per, N);
    int sum = 0;
    for (int i = beg; i < end; ++i) sum += counts[i];
    __shared__ int tmp[T];
    tmp[tid] = sum;
    __syncthreads();
    for (int ofs = 1; ofs < T; ofs <<= 1) {
        int v = (tid >= ofs) ? tmp[tid - ofs] : 0;
        __syncthreads();
        tmp[tid] += v;
        __syncthreads();
    }
    int run = tmp[tid] - sum;              // exclusive prefix of this chunk
    for (int i = beg; i < end; ++i) {
        offsets[i] = run;
        cursor[i]  = run;
        run += counts[i];
    }
    if (tid == T - 1) offsets[N] = run;    // == E (last chunk is empty/last)
}

// ---------------------------------------------------------------------------
// scatter: bucket edge ids by dst.
// ---------------------------------------------------------------------------
__global__ void scatter_kernel(const int* __restrict__ mp,
                               int* __restrict__ cursor,
                               int* __restrict__ elist, int E) {
    int e = blockIdx.x * blockDim.x + threadIdx.x;
    if (e >= E) return;
    int dst = mp[(size_t)e * 4 + 3];
    int pos = atomicAdd(&cursor[dst], 1);
    elist[pos] = e;
}

// ---------------------------------------------------------------------------
// node: one wave per node. Phase A/B: per-head max & expsum via 8-lane groups
// (lane = j*8 + h). Phase C: lane = dim d, acc[8] outer-product accumulate.
// ---------------------------------------------------------------------------
__global__ void node_kernel(const float* __restrict__ hidden,
                            const float* __restrict__ abuf,
                            const int* __restrict__ offsets,
                            const int* __restrict__ elist,
                            float* __restrict__ ft, int N) {
    int wid = (int)((blockIdx.x * blockDim.x + threadIdx.x) >> 6);
    int lane = threadIdx.x & 63;
    if (wid >= N) return;
    int beg = offsets[wid], end = offsets[wid + 1];

    int h = lane & 7, j = lane >> 3;
    float m = -INFINITY;
    for (int p = beg + j; p < end; p += 8)
        m = fmaxf(m, abuf[(size_t)elist[p] * 8 + h]);
    m = fmaxf(m, __shfl_xor(m, 8));
    m = fmaxf(m, __shfl_xor(m, 16));
    m = fmaxf(m, __shfl_xor(m, 32));
    float s = 0.f;
    for (int p = beg + j; p < end; p += 8)
        s += __expf(abuf[(size_t)elist[p] * 8 + h] - m);
    s += __shfl_xor(s, 8);
    s += __shfl_xor(s, 16);
    s += __shfl_xor(s, 32);

    __shared__ float ms[4][8];
    __shared__ float rs[4][8];
    int w = threadIdx.x >> 6;
    if (lane < 8) {
        ms[w][lane] = m;
        rs[w][lane] = (s > 0.f) ? 1.f / s : 0.f;
    }
    // same-wave LDS write->read; compiler inserts lgkmcnt wait

    float acc[8] = {0, 0, 0, 0, 0, 0, 0, 0};
    for (int p = beg; p < end; ++p) {
        int e = elist[p];
        float hval = hidden[(size_t)e * 64 + lane];
#pragma unroll
        for (int hh = 0; hh < 8; ++hh) {
            float att = __expf(abuf[(size_t)e * 8 + hh] - ms[w][hh]) * rs[w][hh];
            acc[hh] += att * hval;
        }
    }
    size_t baseo = (size_t)wid * 512;
#pragma unroll
    for (int hh = 0; hh < 8; ++hh)
        ft[baseo + hh * 64 + lane] = acc[hh];
}

extern "C" void kernel_launch(void* const* d_in, const int* in_sizes, int n_in,
                              void* d_out, int out_size, void* d_ws, size_t ws_size,
                              hipStream_t stream) {
    const int*   mp   = (const int*)d_in[0];
    const int*   ift  = (const int*)d_in[1];
    const float* feat = (const float*)d_in[2];
    const float* rvec = (const float*)d_in[3];
    const float* w1   = (const float*)d_in[4];
    const float* w2   = (const float*)d_in[5];
    int E = in_sizes[0] / 4;
    int N = in_sizes[2] / 64;

    float* out0 = (float*)d_out;
    float* ft   = out0 + N;

    char*  base    = (char*)d_ws;
    float* frv     = (float*)base;                         // 256 floats
    float* hidden  = (float*)(base + 4096);                // E*64 floats
    float* abuf    = hidden + (size_t)E * 64;              // E*8 floats
    int*   counts  = (int*)(abuf + (size_t)E * 8);         // N
    int*   offsets = counts + N;                           // N+1
    int*   cursor  = offsets + N + 1;                      // N
    int*   elist   = cursor + N;                           // E

    init_kernel<<<196, 256, 0, stream>>>(ift, rvec, out0, frv, counts, N);
    edge_kernel<<<(E + 3) / 4, 256, 0, stream>>>(mp, feat, frv, w1, w2,
                                                 hidden, abuf, counts, E);
    scan_kernel<<<1, 1024, 0, stream>>>(counts, offsets, cursor, N);
    scatter_kernel<<<(E + 255) / 256, 256, 0, stream>>>(mp, cursor, elist, E);
    node_kernel<<<(N + 3) / 4, 256, 0, stream>>>(hidden, abuf, offsets, elist,
                                                 ft, N);
}

// Round 3
// 219.585 us; speedup vs baseline: 1.2995x; 1.2995x over previous
//
#include <hip/hip_runtime.h>
#include <hip/hip_bf16.h>
#include <math.h>

#define ALPHA 0.01f

// ---------------------------------------------------------------------------
// init: zero counts, emit output0 (= iftargets[:,0] as float), compute frv.
// frv[l][p] = product of normalized rvec[ETYPES[l..2]][p]; frv[3] = 1+0j.
// Layout frv[l*64 + p*2 + c].
// ---------------------------------------------------------------------------
__global__ void init_kernel(const int* __restrict__ ift,
                            const float* __restrict__ rvec,
                            float* __restrict__ out0,
                            float* __restrict__ frv,
                            int* __restrict__ counts, int N) {
    int gid = blockIdx.x * blockDim.x + threadIdx.x;
    for (int i = gid; i < N; i += gridDim.x * blockDim.x) {
        counts[i] = 0;
        out0[i] = (float)ift[2 * i];
    }
    if (blockIdx.x == 0 && threadIdx.x < 32) {
        int p = threadIdx.x;
        float fr = 1.f, fi = 0.f;
        frv[3 * 64 + 2 * p]     = 1.f;
        frv[3 * 64 + 2 * p + 1] = 0.f;
        for (int l = 2; l >= 0; --l) {
            float rr = rvec[l * 64 + 2 * p];
            float ri = rvec[l * 64 + 2 * p + 1];
            float inv = rsqrtf(rr * rr + ri * ri);
            rr *= inv; ri *= inv;
            float nr = fr * rr - fi * ri;
            float ni = fr * ri + fi * rr;
            fr = nr; fi = ni;
            frv[l * 64 + 2 * p]     = fr;
            frv[l * 64 + 2 * p + 1] = fi;
        }
    }
}

// ---------------------------------------------------------------------------
// prep: per-node logit tables. q[n][0..7]  = feat[n]·w1[h]
//                              q[n][8+l*8+h] = 0.25 * feat[n]·(rot_l^* w2[h])
// rot_l^* maps (w0,w1) -> (w0*fr + w1*fi, w1*fr - w0*fi).
// Thread per node; weights transposed into LDS as wt[d][40] for float4 reads.
// ---------------------------------------------------------------------------
__global__ void prep_kernel(const float* __restrict__ feat,
                            const float* __restrict__ w1,
                            const float* __restrict__ w2,
                            const float* __restrict__ frv,
                            float* __restrict__ q, int N) {
    __shared__ float wt[64 * 40];
    int tid = threadIdx.x;
    for (int i = tid; i < 512; i += 256) {          // w1 part
        int h = i >> 6, d = i & 63;
        wt[d * 40 + h] = w1[i];
    }
    for (int i = tid; i < 2048; i += 256) {         // rotated w2 part
        int l = i >> 9, r = i & 511, h = r >> 6, d = r & 63;
        float fr = frv[l * 64 + (d & ~1)];
        float fi = frv[l * 64 + (d | 1)];
        float sgn = (d & 1) ? -1.f : 1.f;
        float v = w2[h * 64 + d] * fr + sgn * w2[h * 64 + (d ^ 1)] * fi;
        wt[d * 40 + 8 + l * 8 + h] = 0.25f * v;
    }
    __syncthreads();
    int n = blockIdx.x * blockDim.x + tid;
    if (n >= N) return;
    float4 acc[10];
#pragma unroll
    for (int k = 0; k < 10; ++k) acc[k] = make_float4(0.f, 0.f, 0.f, 0.f);
    const float* row = feat + (size_t)n * 64;
    for (int d = 0; d < 64; ++d) {
        float x = row[d];
        const float4* w4 = (const float4*)(wt + d * 40);
#pragma unroll
        for (int k = 0; k < 10; ++k) {
            float4 w = w4[k];
            acc[k].x += x * w.x; acc[k].y += x * w.y;
            acc[k].z += x * w.z; acc[k].w += x * w.w;
        }
    }
    float4* qo = (float4*)(q + (size_t)n * 40);
#pragma unroll
    for (int k = 0; k < 10; ++k) qo[k] = acc[k];
}

// ---------------------------------------------------------------------------
// edge logits: thread per edge. a[h] = leaky(q1[dst][h] + sum_l q2[src_l][l][h])
// ---------------------------------------------------------------------------
__global__ void edge_logit_kernel(const int* __restrict__ mp,
                                  const float* __restrict__ q,
                                  float* __restrict__ abuf,
                                  int* __restrict__ counts, int E) {
    int e = blockIdx.x * blockDim.x + threadIdx.x;
    if (e >= E) return;
    const int4 m4 = ((const int4*)mp)[e];
    const float4* qc = (const float4*)(q + (size_t)m4.w * 40);
    float4 a0 = qc[0], a1 = qc[1];
    int idx[4] = {m4.x, m4.y, m4.z, m4.w};
#pragma unroll
    for (int l = 0; l < 4; ++l) {
        const float4* ql = (const float4*)(q + (size_t)idx[l] * 40 + 8 + l * 8);
        float4 b0 = ql[0], b1 = ql[1];
        a0.x += b0.x; a0.y += b0.y; a0.z += b0.z; a0.w += b0.w;
        a1.x += b1.x; a1.y += b1.y; a1.z += b1.z; a1.w += b1.w;
    }
    a0.x = a0.x > 0.f ? a0.x : ALPHA * a0.x;
    a0.y = a0.y > 0.f ? a0.y : ALPHA * a0.y;
    a0.z = a0.z > 0.f ? a0.z : ALPHA * a0.z;
    a0.w = a0.w > 0.f ? a0.w : ALPHA * a0.w;
    a1.x = a1.x > 0.f ? a1.x : ALPHA * a1.x;
    a1.y = a1.y > 0.f ? a1.y : ALPHA * a1.y;
    a1.z = a1.z > 0.f ? a1.z : ALPHA * a1.z;
    a1.w = a1.w > 0.f ? a1.w : ALPHA * a1.w;
    float4* ao = (float4*)(abuf + (size_t)e * 8);
    ao[0] = a0; ao[1] = a1;
    atomicAdd(&counts[m4.w], 1);
}

// ---------------------------------------------------------------------------
// scan: single block, 1024 threads. Exclusive scan -> offsets[N+1] + cursor.
// ---------------------------------------------------------------------------
__global__ void scan_kernel(const int* __restrict__ counts,
                            int* __restrict__ offsets,
                            int* __restrict__ cursor, int N) {
    const int T = 1024;
    int tid = threadIdx.x;
    int per = (N + T - 1) / T;
    int beg = tid * per;
    int end = min(beg + per, N);
    int sum = 0;
    for (int i = beg; i < end; ++i) sum += counts[i];
    __shared__ int tmp[T];
    tmp[tid] = sum;
    __syncthreads();
    for (int ofs = 1; ofs < T; ofs <<= 1) {
        int v = (tid >= ofs) ? tmp[tid - ofs] : 0;
        __syncthreads();
        tmp[tid] += v;
        __syncthreads();
    }
    int run = tmp[tid] - sum;
    for (int i = beg; i < end; ++i) {
        offsets[i] = run;
        cursor[i]  = run;
        run += counts[i];
    }
    if (tid == T - 1) offsets[N] = run;
}

// ---------------------------------------------------------------------------
// scatter: permute mp rows and logits into CSR (dst-grouped) order.
// ---------------------------------------------------------------------------
__global__ void scatter_kernel(const int* __restrict__ mp,
                               const float* __restrict__ abuf,
                               int* __restrict__ cursor,
                               int* __restrict__ mpperm,
                               float* __restrict__ aperm, int E) {
    int e = blockIdx.x * blockDim.x + threadIdx.x;
    if (e >= E) return;
    const int4 m4 = ((const int4*)mp)[e];
    int pos = atomicAdd(&cursor[m4.w], 1);
    ((int4*)mpperm)[pos] = m4;
    const float4* ab = (const float4*)(abuf + (size_t)e * 8);
    float4 b0 = ab[0], b1 = ab[1];
    float4* ap = (float4*)(aperm + (size_t)pos * 8);
    ap[0] = b0; ap[1] = b1;
}

// ---------------------------------------------------------------------------
// node: one wave per node. Softmax over CSR segment (coalesced aperm reads),
// then per edge: gather 4 feat rows, rotate in-register, accumulate acc[8].
// hidden is never materialized.
// ---------------------------------------------------------------------------
__global__ void node_kernel(const float* __restrict__ feat,
                            const float* __restrict__ frv,
                            const float* __restrict__ aperm,
                            const int* __restrict__ mpperm,
                            const int* __restrict__ offsets,
                            float* __restrict__ ft, int N) {
    int wid = (int)((blockIdx.x * blockDim.x + threadIdx.x) >> 6);
    int lane = threadIdx.x & 63;
    if (wid >= N) return;
    int beg = offsets[wid], end = offsets[wid + 1];

    // phase A/B: per-head max and expsum. 64 lanes cover 8 edges/iter
    // (stride 64 floats); lane's head h = lane & 7 is constant across iters.
    int h = lane & 7;
    float m = -INFINITY;
    for (int idx = beg * 8 + lane; idx < end * 8; idx += 64)
        m = fmaxf(m, aperm[idx]);
    m = fmaxf(m, __shfl_xor(m, 8));
    m = fmaxf(m, __shfl_xor(m, 16));
    m = fmaxf(m, __shfl_xor(m, 32));
    float s = 0.f;
    for (int idx = beg * 8 + lane; idx < end * 8; idx += 64)
        s += __expf(aperm[idx] - m);
    s += __shfl_xor(s, 8);
    s += __shfl_xor(s, 16);
    s += __shfl_xor(s, 32);

    __shared__ float ms[4][8];
    __shared__ float rs[4][8];
    int w = threadIdx.x >> 6;
    if (lane < 8) {
        ms[w][lane] = m;
        rs[w][lane] = (s > 0.f) ? 1.f / s : 0.f;
    }
    // same-wave LDS write->read; compiler inserts lgkmcnt wait

    // per-lane rotation constants (lane = feature dim)
    float sgn = (lane & 1) ? 1.f : -1.f;
    float fr0[4], fi0[4];
#pragma unroll
    for (int l = 0; l < 4; ++l) {
        fr0[l] = frv[l * 64 + (lane & ~1)];
        fi0[l] = frv[l * 64 + (lane | 1)];
    }

    float acc[8] = {0, 0, 0, 0, 0, 0, 0, 0};
    for (int p = beg; p < end; ++p) {
        const int4 m4 = ((const int4*)mpperm)[p];
        float att[8];
#pragma unroll
        for (int hh = 0; hh < 8; ++hh)
            att[hh] = __expf(aperm[(size_t)p * 8 + hh] - ms[w][hh]);
        int idx4[4] = {m4.x, m4.y, m4.z, m4.w};
        float hv = 0.f;
#pragma unroll
        for (int l = 0; l < 4; ++l) {
            float x = feat[(size_t)idx4[l] * 64 + lane];
            float partner = __shfl_xor(x, 1);
            hv += x * fr0[l] + sgn * partner * fi0[l];
        }
        hv *= 0.25f;
#pragma unroll
        for (int hh = 0; hh < 8; ++hh)
            acc[hh] += att[hh] * hv;
    }
    size_t baseo = (size_t)wid * 512;
#pragma unroll
    for (int hh = 0; hh < 8; ++hh)
        ft[baseo + hh * 64 + lane] = acc[hh] * rs[w][hh];
}

extern "C" void kernel_launch(void* const* d_in, const int* in_sizes, int n_in,
                              void* d_out, int out_size, void* d_ws, size_t ws_size,
                              hipStream_t stream) {
    const int*   mp   = (const int*)d_in[0];
    const int*   ift  = (const int*)d_in[1];
    const float* feat = (const float*)d_in[2];
    const float* rvec = (const float*)d_in[3];
    const float* w1   = (const float*)d_in[4];
    const float* w2   = (const float*)d_in[5];
    int E = in_sizes[0] / 4;
    int N = in_sizes[2] / 64;

    float* out0 = (float*)d_out;
    float* ft   = out0 + N;

    float* fp      = (float*)d_ws;
    float* frv     = fp;                                   // 256
    float* q       = frv + 256;                            // N*40
    float* abuf    = q + (size_t)N * 40;                   // E*8
    float* aperm   = abuf + (size_t)E * 8;                 // E*8
    int*   mpperm  = (int*)(aperm + (size_t)E * 8);        // E*4 (16B-aligned)
    int*   counts  = mpperm + (size_t)E * 4;               // N
    int*   offsets = counts + N;                           // N+1
    int*   cursor  = offsets + N + 1;                      // N

    init_kernel<<<196, 256, 0, stream>>>(ift, rvec, out0, frv, counts, N);
    prep_kernel<<<(N + 255) / 256, 256, 0, stream>>>(feat, w1, w2, frv, q, N);
    edge_logit_kernel<<<(E + 255) / 256, 256, 0, stream>>>(mp, q, abuf, counts, E);
    scan_kernel<<<1, 1024, 0, stream>>>(counts, offsets, cursor, N);
    scatter_kernel<<<(E + 255) / 256, 256, 0, stream>>>(mp, abuf, cursor,
                                                        mpperm, aperm, E);
    node_kernel<<<(N + 3) / 4, 256, 0, stream>>>(feat, frv, aperm, mpperm,
                                                 offsets, ft, N);
}

// Round 4
// 118.867 us; speedup vs baseline: 2.4006x; 1.8473x over previous
//
#include <hip/hip_runtime.h>
#include <hip/hip_bf16.h>
#include <math.h>

#define ALPHA 0.01f

// ---------------------------------------------------------------------------
// init: zero counts, emit output0 (= iftargets[:,0] as float), compute frv.
// frv[l][p] = product of normalized rvec[ETYPES[l..2]][p]; frv[3] = 1+0j.
// Layout frv[l*64 + p*2 + c].
// ---------------------------------------------------------------------------
__global__ void init_kernel(const int* __restrict__ ift,
                            const float* __restrict__ rvec,
                            float* __restrict__ out0,
                            float* __restrict__ frv,
                            int* __restrict__ counts, int N) {
    int gid = blockIdx.x * blockDim.x + threadIdx.x;
    for (int i = gid; i < N; i += gridDim.x * blockDim.x) {
        counts[i] = 0;
        out0[i] = (float)ift[2 * i];
    }
    if (blockIdx.x == 0 && threadIdx.x < 32) {
        int p = threadIdx.x;
        float fr = 1.f, fi = 0.f;
        frv[3 * 64 + 2 * p]     = 1.f;
        frv[3 * 64 + 2 * p + 1] = 0.f;
        for (int l = 2; l >= 0; --l) {
            float rr = rvec[l * 64 + 2 * p];
            float ri = rvec[l * 64 + 2 * p + 1];
            float inv = rsqrtf(rr * rr + ri * ri);
            rr *= inv; ri *= inv;
            float nr = fr * rr - fi * ri;
            float ni = fr * ri + fi * rr;
            fr = nr; fi = ni;
            frv[l * 64 + 2 * p]     = fr;
            frv[l * 64 + 2 * p + 1] = fi;
        }
    }
}

// ---------------------------------------------------------------------------
// prep: per-node logit tables. q[n][0..7]  = feat[n]·w1[h]
//                              q[n][8+l*8+h] = 0.25 * feat[n]·(rot_l^* w2[h])
// rot_l^* maps (w0,w1) -> (w0*fr + w1*fi, w1*fr - w0*fi).
// Thread per node; weights transposed into LDS as wt[d][40] for float4 reads.
// ---------------------------------------------------------------------------
__global__ void prep_kernel(const float* __restrict__ feat,
                            const float* __restrict__ w1,
                            const float* __restrict__ w2,
                            const float* __restrict__ frv,
                            float* __restrict__ q, int N) {
    __shared__ float wt[64 * 40];
    int tid = threadIdx.x;
    for (int i = tid; i < 512; i += 256) {          // w1 part
        int h = i >> 6, d = i & 63;
        wt[d * 40 + h] = w1[i];
    }
    for (int i = tid; i < 2048; i += 256) {         // rotated w2 part
        int l = i >> 9, r = i & 511, h = r >> 6, d = r & 63;
        float fr = frv[l * 64 + (d & ~1)];
        float fi = frv[l * 64 + (d | 1)];
        float sgn = (d & 1) ? -1.f : 1.f;
        float v = w2[h * 64 + d] * fr + sgn * w2[h * 64 + (d ^ 1)] * fi;
        wt[d * 40 + 8 + l * 8 + h] = 0.25f * v;
    }
    __syncthreads();
    int n = blockIdx.x * blockDim.x + tid;
    if (n >= N) return;
    float4 acc[10];
#pragma unroll
    for (int k = 0; k < 10; ++k) acc[k] = make_float4(0.f, 0.f, 0.f, 0.f);
    const float* row = feat + (size_t)n * 64;
    for (int d = 0; d < 64; ++d) {
        float x = row[d];
        const float4* w4 = (const float4*)(wt + d * 40);
#pragma unroll
        for (int k = 0; k < 10; ++k) {
            float4 w = w4[k];
            acc[k].x += x * w.x; acc[k].y += x * w.y;
            acc[k].z += x * w.z; acc[k].w += x * w.w;
        }
    }
    float4* qo = (float4*)(q + (size_t)n * 40);
#pragma unroll
    for (int k = 0; k < 10; ++k) qo[k] = acc[k];
}

// ---------------------------------------------------------------------------
// edge logits: thread per edge. a[h] = leaky(q1[dst][h] + sum_l q2[src_l][l][h])
// ---------------------------------------------------------------------------
__global__ void edge_logit_kernel(const int* __restrict__ mp,
                                  const float* __restrict__ q,
                                  float* __restrict__ abuf,
                                  int* __restrict__ counts, int E) {
    int e = blockIdx.x * blockDim.x + threadIdx.x;
    if (e >= E) return;
    const int4 m4 = ((const int4*)mp)[e];
    const float4* qc = (const float4*)(q + (size_t)m4.w * 40);
    float4 a0 = qc[0], a1 = qc[1];
    int idx[4] = {m4.x, m4.y, m4.z, m4.w};
#pragma unroll
    for (int l = 0; l < 4; ++l) {
        const float4* ql = (const float4*)(q + (size_t)idx[l] * 40 + 8 + l * 8);
        float4 b0 = ql[0], b1 = ql[1];
        a0.x += b0.x; a0.y += b0.y; a0.z += b0.z; a0.w += b0.w;
        a1.x += b1.x; a1.y += b1.y; a1.z += b1.z; a1.w += b1.w;
    }
    a0.x = a0.x > 0.f ? a0.x : ALPHA * a0.x;
    a0.y = a0.y > 0.f ? a0.y : ALPHA * a0.y;
    a0.z = a0.z > 0.f ? a0.z : ALPHA * a0.z;
    a0.w = a0.w > 0.f ? a0.w : ALPHA * a0.w;
    a1.x = a1.x > 0.f ? a1.x : ALPHA * a1.x;
    a1.y = a1.y > 0.f ? a1.y : ALPHA * a1.y;
    a1.z = a1.z > 0.f ? a1.z : ALPHA * a1.z;
    a1.w = a1.w > 0.f ? a1.w : ALPHA * a1.w;
    float4* ao = (float4*)(abuf + (size_t)e * 8);
    ao[0] = a0; ao[1] = a1;
    atomicAdd(&counts[m4.w], 1);
}

// ---------------------------------------------------------------------------
// hierarchical scan, 256-element chunks.
// scan1: per-block exclusive scan + block sum.  scan2: scan of block sums
// (single block; B<=256).  scan3: add block prefix -> offsets + cursor.
// ---------------------------------------------------------------------------
__global__ void scan1_kernel(const int* __restrict__ counts,
                             int* __restrict__ offsets,
                             int* __restrict__ bsums, int N) {
    __shared__ int tmp[256];
    int tid = threadIdx.x;
    int gid = blockIdx.x * 256 + tid;
    int v = (gid < N) ? counts[gid] : 0;
    tmp[tid] = v;
    __syncthreads();
#pragma unroll
    for (int ofs = 1; ofs < 256; ofs <<= 1) {
        int t = (tid >= ofs) ? tmp[tid - ofs] : 0;
        __syncthreads();
        tmp[tid] += t;
        __syncthreads();
    }
    if (gid < N) offsets[gid] = tmp[tid] - v;      // exclusive, block-local
    if (tid == 255) bsums[blockIdx.x] = tmp[255];
}

__global__ void scan2_kernel(int* __restrict__ bsums, int B) {
    __shared__ int tmp[256];
    int tid = threadIdx.x;
    int v = (tid < B) ? bsums[tid] : 0;
    tmp[tid] = v;
    __syncthreads();
#pragma unroll
    for (int ofs = 1; ofs < 256; ofs <<= 1) {
        int t = (tid >= ofs) ? tmp[tid - ofs] : 0;
        __syncthreads();
        tmp[tid] += t;
        __syncthreads();
    }
    if (tid < B) bsums[tid] = tmp[tid] - v;        // exclusive block prefix
}

__global__ void scan3_kernel(int* __restrict__ offsets,
                             int* __restrict__ cursor,
                             const int* __restrict__ bsums, int N, int E) {
    int gid = blockIdx.x * 256 + threadIdx.x;
    if (gid < N) {
        int o = offsets[gid] + bsums[gid >> 8];
        offsets[gid] = o;
        cursor[gid]  = o;
    }
    if (gid == 0) offsets[N] = E;
}

// ---------------------------------------------------------------------------
// scatter: permute mp rows and logits into CSR (dst-grouped) order.
// ---------------------------------------------------------------------------
__global__ void scatter_kernel(const int* __restrict__ mp,
                               const float* __restrict__ abuf,
                               int* __restrict__ cursor,
                               int* __restrict__ mpperm,
                               float* __restrict__ aperm, int E) {
    int e = blockIdx.x * blockDim.x + threadIdx.x;
    if (e >= E) return;
    const int4 m4 = ((const int4*)mp)[e];
    int pos = atomicAdd(&cursor[m4.w], 1);
    ((int4*)mpperm)[pos] = m4;
    const float4* ab = (const float4*)(abuf + (size_t)e * 8);
    float4 b0 = ab[0], b1 = ab[1];
    float4* ap = (float4*)(aperm + (size_t)pos * 8);
    ap[0] = b0; ap[1] = b1;
}

// ---------------------------------------------------------------------------
// node: one wave per node. Softmax over CSR segment (coalesced aperm reads),
// then per edge: gather 4 feat rows, rotate in-register, accumulate acc[8].
// hidden is never materialized.
// ---------------------------------------------------------------------------
__global__ void node_kernel(const float* __restrict__ feat,
                            const float* __restrict__ frv,
                            const float* __restrict__ aperm,
                            const int* __restrict__ mpperm,
                            const int* __restrict__ offsets,
                            float* __restrict__ ft, int N) {
    int wid = (int)((blockIdx.x * blockDim.x + threadIdx.x) >> 6);
    int lane = threadIdx.x & 63;
    if (wid >= N) return;
    int beg = offsets[wid], end = offsets[wid + 1];

    // phase A/B: per-head max and expsum. 64 lanes cover 8 edges/iter
    // (stride 64 floats); lane's head h = lane & 7 is constant across iters.
    int h = lane & 7;
    float m = -INFINITY;
    for (int idx = beg * 8 + lane; idx < end * 8; idx += 64)
        m = fmaxf(m, aperm[idx]);
    m = fmaxf(m, __shfl_xor(m, 8));
    m = fmaxf(m, __shfl_xor(m, 16));
    m = fmaxf(m, __shfl_xor(m, 32));
    float s = 0.f;
    for (int idx = beg * 8 + lane; idx < end * 8; idx += 64)
        s += __expf(aperm[idx] - m);
    s += __shfl_xor(s, 8);
    s += __shfl_xor(s, 16);
    s += __shfl_xor(s, 32);

    __shared__ float ms[4][8];
    __shared__ float rs[4][8];
    int w = threadIdx.x >> 6;
    if (lane < 8) {
        ms[w][lane] = m;
        rs[w][lane] = (s > 0.f) ? 1.f / s : 0.f;
    }
    // same-wave LDS write->read; compiler inserts lgkmcnt wait

    // per-lane rotation constants (lane = feature dim)
    float sgn = (lane & 1) ? 1.f : -1.f;
    float fr0[4], fi0[4];
#pragma unroll
    for (int l = 0; l < 4; ++l) {
        fr0[l] = frv[l * 64 + (lane & ~1)];
        fi0[l] = frv[l * 64 + (lane | 1)];
    }

    float acc[8] = {0, 0, 0, 0, 0, 0, 0, 0};
    for (int p = beg; p < end; ++p) {
        const int4 m4 = ((const int4*)mpperm)[p];
        float att[8];
#pragma unroll
        for (int hh = 0; hh < 8; ++hh)
            att[hh] = __expf(aperm[(size_t)p * 8 + hh] - ms[w][hh]);
        int idx4[4] = {m4.x, m4.y, m4.z, m4.w};
        float hv = 0.f;
#pragma unroll
        for (int l = 0; l < 4; ++l) {
            float x = feat[(size_t)idx4[l] * 64 + lane];
            float partner = __shfl_xor(x, 1);
            hv += x * fr0[l] + sgn * partner * fi0[l];
        }
        hv *= 0.25f;
#pragma unroll
        for (int hh = 0; hh < 8; ++hh)
            acc[hh] += att[hh] * hv;
    }
    size_t baseo = (size_t)wid * 512;
#pragma unroll
    for (int hh = 0; hh < 8; ++hh)
        ft[baseo + hh * 64 + lane] = acc[hh] * rs[w][hh];
}

extern "C" void kernel_launch(void* const* d_in, const int* in_sizes, int n_in,
                              void* d_out, int out_size, void* d_ws, size_t ws_size,
                              hipStream_t stream) {
    const int*   mp   = (const int*)d_in[0];
    const int*   ift  = (const int*)d_in[1];
    const float* feat = (const float*)d_in[2];
    const float* rvec = (const float*)d_in[3];
    const float* w1   = (const float*)d_in[4];
    const float* w2   = (const float*)d_in[5];
    int E = in_sizes[0] / 4;
    int N = in_sizes[2] / 64;

    float* out0 = (float*)d_out;
    float* ft   = out0 + N;

    float* fp      = (float*)d_ws;
    float* frv     = fp;                                   // 256
    float* q       = frv + 256;                            // N*40
    float* abuf    = q + (size_t)N * 40;                   // E*8
    float* aperm   = abuf + (size_t)E * 8;                 // E*8
    int*   mpperm  = (int*)(aperm + (size_t)E * 8);        // E*4 (16B-aligned)
    int*   counts  = mpperm + (size_t)E * 4;               // N
    int*   offsets = counts + N;                           // N+1
    int*   cursor  = offsets + N + 1;                      // N
    int*   bsums   = cursor + N;                           // nblk(N)

    int nblkN = (N + 255) / 256;

    init_kernel<<<196, 256, 0, stream>>>(ift, rvec, out0, frv, counts, N);
    prep_kernel<<<nblkN, 256, 0, stream>>>(feat, w1, w2, frv, q, N);
    edge_logit_kernel<<<(E + 255) / 256, 256, 0, stream>>>(mp, q, abuf, counts, E);
    scan1_kernel<<<nblkN, 256, 0, stream>>>(counts, offsets, bsums, N);
    scan2_kernel<<<1, 256, 0, stream>>>(bsums, nblkN);
    scan3_kernel<<<nblkN, 256, 0, stream>>>(offsets, cursor, bsums, N, E);
    scatter_kernel<<<(E + 255) / 256, 256, 0, stream>>>(mp, abuf, cursor,
                                                        mpperm, aperm, E);
    node_kernel<<<(N + 3) / 4, 256, 0, stream>>>(feat, frv, aperm, mpperm,
                                                 offsets, ft, N);
}